// Round 7
// baseline (803.332 us; speedup 1.0000x reference)
//
#include <hip/hip_runtime.h>

// GrCNN: B=32, L=128, D=256, 127 sequential levels.
// Round 7: row-slab + SUPERSTEP batching. 256 blocks = (b, h), 8 waves.
// Per superstep (8 levels): import 8 boundary rows (16..23) once, advance
// 8 levels locally (tile0 = own rows 0..15, tile1 = overlap rows 16..22-j,
// recomputed redundantly & bit-identically), export rows 0..7 once.
// Gates: split-K MFMA on waves 0..3 (reuse their A-frags, gate-B from LDS),
// preacts broadcast via LDS -> no per-wave gate redundancy, no shfl storm.
// W central fragments (wf0,wf1 = 128 VGPR) resident per wave.

#define B_ 32
#define L_ 128
#define D_ 256
#define NTHR 512
#define RS 8
#define LOG2E 1.4426950408889634f

typedef _Float16 half8 __attribute__((ext_vector_type(8)));
typedef float f32x4 __attribute__((ext_vector_type(4)));

#define SWZ(o)  ((o) ^ ((((o) >> 9) & 7) << 4))
#define SWZW(o) ((o) ^ ((((o) >> 10) & 7) << 4))
#define MFMA16 __builtin_amdgcn_mfma_f32_16x16x32_f16

// ---- WT[272][512] fp16: col j -> 512 k (k<256: Wl/Gl row k, else Wr/Gr) ----
__global__ void prep_wt(const float* __restrict__ Wl, const float* __restrict__ Wr,
                        const float* __restrict__ Gl, const float* __restrict__ Gr,
                        _Float16* __restrict__ WT) {
    int j = blockIdx.x;
    for (int k = threadIdx.x; k < 512; k += 256) {
        float v = 0.f;
        if (j < 256) v = (k < 256) ? Wl[k * 256 + j] : Wr[(k - 256) * 256 + j];
        else { int jj = j - 256; if (jj < 3) v = (k < 256) ? Gl[k * 3 + jj] : Gr[(k - 256) * 3 + jj]; }
        WT[(size_t)j * 512 + k] = (_Float16)v;
    }
}

// ---- init: flags=0, acks=-1, enc=0, level-0 col max ----
__global__ void init_misc(const float* __restrict__ x, float* __restrict__ out,
                          unsigned* __restrict__ enc, int* __restrict__ flags) {
    int b = blockIdx.x, c = threadIdx.x;
    if (b == 0) for (int i = c; i < 2 * 256 * 16; i += 256)
        flags[i] = (i < 256 * 16) ? 0 : -1;
    for (int k = 0; k < L_; ++k) enc[((size_t)b * L_ + k) * D_ + c] = 0u;
    float m = -3.4e38f;
    for (int row = 0; row < L_; ++row)
        m = fmaxf(m, x[((size_t)b * L_ + row) * D_ + c]);
    out[(size_t)b * L_ * D_ + c] = m;
}

// ---- decode: enc -> out for levels 1..127 ----
__global__ void decode_out(const unsigned* __restrict__ enc, float* __restrict__ out) {
    for (size_t i = (size_t)blockIdx.x * 256 + threadIdx.x; i < (size_t)32 * 128 * 256;
         i += (size_t)gridDim.x * 256) {
        unsigned k = (unsigned)((i >> 8) & 127);
        if (k == 0) continue;
        unsigned u = enc[i];
        unsigned bitsv = (u & 0x80000000u) ? (u & 0x7FFFFFFFu) : ~u;
        out[i] = __builtin_bit_cast(float, bitsv);
    }
}

__global__ __launch_bounds__(NTHR, 2) void grcnn_main(
    const float* __restrict__ x, const _Float16* __restrict__ WT,
    const float* __restrict__ Wb, const float* __restrict__ Gb,
    unsigned* __restrict__ enc, unsigned long long* __restrict__ brow,
    int* __restrict__ flags)
{
    // buf0/buf1: 33 rows * 512B (rows 0..32, swizzled). wst: gate-B 16KB. gat: preacts.
    __shared__ alignas(16) char lds[16896 * 2 + 16384 + 1536];
    char* buf0 = lds;
    char* buf1 = lds + 16896;
    char* wst  = lds + 33792;
    float* gat = (float*)(lds + 33792 + 16384);   // [tile][row][part][4] stride 12 floats/row

    const int tid = threadIdx.x;
    const int b = blockIdx.x & 31, h = blockIdx.x >> 5;
    const int w = tid >> 6, l = tid & 63, lr = l & 15, q = l >> 4;
    const int cw = w * 32;

    // ---- resident central W fragments (128 VGPR) ----
    half8 wf0[16], wf1[16];
    #pragma unroll
    for (int s = 0; s < 16; ++s) {
        const _Float16* p = WT + s * 32 + q * 8;
        wf0[s] = *(const half8*)(p + (size_t)(cw + lr) * 512);
        wf1[s] = *(const half8*)(p + (size_t)(cw + 16 + lr) * 512);
    }
    // one-hot extraction frags (tile NT extracts S[row][cw+NT*16+lr])
    half8 oh0 = {}, oh1 = {};
    {
        _Float16 one = (_Float16)1.0f;
        #pragma unroll
        for (int j = 0; j < 8; ++j) if (j == (lr & 7)) {
            if (q == (lr >> 3))     oh0[j] = one;
            if (q == 2 + (lr >> 3)) oh1[j] = one;
        }
    }
    const float wb0 = Wb[cw + lr], wb1 = Wb[cw + 16 + lr];
    const float gbi0 = Gb[0], gbi1 = Gb[1], gbi2 = Gb[2];

    int* flagA = flags;
    int* ackA  = flags + 256 * 16;

    // ---- stage gate-B (WT cols 256..271) into wst: [col][k], swizzled ----
    for (int ch = tid; ch < 2048; ch += NTHR) {
        int col = ch >> 6, kc = ch & 63;
        half8 v = *(const half8*)(WT + (size_t)(256 + col) * 512 + kc * 8);
        int off = col * 1024 + kc * 16;
        *(half8*)(wst + SWZW(off)) = v;
    }
    // ---- stage x rows 16h..16h+32 (clamped) into BOTH buffers ----
    for (int ch = tid; ch < 33 * 32; ch += NTHR) {
        int row = ch >> 5, kc = ch & 31;
        int grow = 16 * h + row; if (grow > 127) grow = 127;
        const float* xp = x + ((size_t)b * L_ + grow) * D_ + kc * 8;
        half8 v;
        #pragma unroll
        for (int j = 0; j < 8; ++j) v[j] = (_Float16)xp[j];
        int off = SWZ(row * 512 + kc * 16);
        *(half8*)(buf0 + off) = v;
        *(half8*)(buf1 + off) = v;
    }
    __syncthreads();

    char* src = buf0;
    char* dst = buf1;

    for (int sigma = 0;; ++sigma) {
        const int T = RS * sigma;
        const int M = 127 - T - 16 * h;
        if (M <= 0) break;
        const int jmax = (127 - T < RS) ? (127 - T) : RS;
        const bool doImp = (sigma >= 1) && (M >= 16);
        const bool t1base = (M >= 17);

        // ---- import 8 boundary rows (level-T rows 16h+16..16h+23) ----
        if (doImp) {
            if (l == 0) {
                while (__hip_atomic_load(&flagA[(b * 8 + h + 1) * 16],
                        __ATOMIC_RELAXED, __HIP_MEMORY_SCOPE_AGENT) < sigma)
                    __builtin_amdgcn_s_sleep(1);
            }
            const unsigned long long* bp =
                brow + ((((size_t)((sigma - 1) & 1) * 32 + b) * 8 + (h + 1)) * 8 + w) * 64 + l;
            unsigned long long iv =
                __hip_atomic_load(bp, __ATOMIC_RELAXED, __HIP_MEMORY_SCOPE_AGENT);
            *(unsigned long long*)(src + SWZ((16 + w) * 512 + l * 8)) = iv;
            __syncthreads();
            if (tid == 0)
                __hip_atomic_store(&ackA[(b * 8 + h) * 16], sigma - 1,
                                   __ATOMIC_RELAXED, __HIP_MEMORY_SCOPE_AGENT);
        }

        for (int j = 0; j < jmax; ++j) {
            const int n = 127 - T - j;
            const bool t1 = t1base && (j <= 6);

            // ================= phase A: MFMA =================
            f32x4 a00 = {}, a01 = {}, a10 = {}, a11 = {}, ag = {}, z = {};
            f32x4 e0 = {}, e1 = {}, e0b = {}, e1b = {};
            #pragma unroll
            for (int s = 0; s < 16; ++s) {
                half8 av = *(const half8*)(src + SWZ(lr * 512 + s * 64 + q * 16));
                a00 = MFMA16(av, wf0[s], a00, 0, 0, 0);
                a01 = MFMA16(av, wf1[s], a01, 0, 0, 0);
                if ((w == 0 && s < 8) || (w == 2 && s >= 8)) {
                    half8 gv = *(const half8*)(wst + SWZW(lr * 1024 + s * 64 + q * 16));
                    ag = MFMA16(av, gv, ag, 0, 0, 0);
                }
            }
            {
                half8 ax = *(const half8*)(src + SWZ(lr * 512 + w * 64 + q * 16));
                e0 = MFMA16(ax, oh0, z, 0, 0, 0);
                e1 = MFMA16(ax, oh1, z, 0, 0, 0);
            }
            if (t1) {
                #pragma unroll
                for (int s = 0; s < 16; ++s) {
                    half8 av = *(const half8*)(src + SWZ((16 + lr) * 512 + s * 64 + q * 16));
                    a10 = MFMA16(av, wf0[s], a10, 0, 0, 0);
                    a11 = MFMA16(av, wf1[s], a11, 0, 0, 0);
                    if ((w == 1 && s < 8) || (w == 3 && s >= 8)) {
                        half8 gv = *(const half8*)(wst + SWZW(lr * 1024 + s * 64 + q * 16));
                        ag = MFMA16(av, gv, ag, 0, 0, 0);
                    }
                }
                half8 ax = *(const half8*)(src + SWZ((16 + lr) * 512 + w * 64 + q * 16));
                e0b = MFMA16(ax, oh0, z, 0, 0, 0);
                e1b = MFMA16(ax, oh1, z, 0, 0, 0);
            }
            // gate preact partials -> LDS (waves 0..3, lanes lr<3)
            if (w < 4 && lr < 3) {
                int tile = w & 1, part = (w >> 1) & 1;
                if (tile == 0 || t1) {
                    #pragma unroll
                    for (int r = 0; r < 4; ++r)
                        gat[tile * 192 + (q * 4 + r) * 12 + part * 4 + lr] = ag[r];
                }
            }
            // boundary-rv shuffles (register/LDS-pipe, pre-barrier)
            int nl = (l + 16) & 63;
            float s0 = __shfl(e0[0], nl, 64);
            float s1 = __shfl(e1[0], nl, 64);
            float s0b = 0.f, s1b = 0.f;
            if (t1) { s0b = __shfl(e0b[0], nl, 64); s1b = __shfl(e1b[0], nl, 64); }

            __syncthreads();   // B1: gate preacts visible

            // ================= phase B: epilogue =================
            float cm0 = -3.4e38f, cm1 = -3.4e38f;

            #define EPI(ACCr, EV, WBV, BLV, SHV, NT, ROW, DO_CM, CMV) {                      \
                float pre = ACCr + WBV;                                                      \
                float exx = exp2f(pre * (2.f * LOG2E));                                      \
                float ce = 1.f - 2.f * __builtin_amdgcn_rcpf(exx + 1.f);                     \
                float lv = EV[r];                                                            \
                float rv = (r < 3) ? EV[(r < 3) ? r + 1 : 0] : (q < 3 ? SHV : BLV);          \
                float nx = g0f * lv + g1f * ce + g2f * rv;                                   \
                if (DO_CM) CMV = fmaxf(CMV, nx);                                             \
                int pdi = __builtin_amdgcn_update_dpp(                                       \
                    0, __builtin_bit_cast(int, nx), 0xB1, 0xF, 0xF, true);                   \
                float pnx = __builtin_bit_cast(float, pdi);                                  \
                unsigned pk = (unsigned)__builtin_bit_cast(unsigned short, (_Float16)nx)     \
                    | ((unsigned)__builtin_bit_cast(unsigned short, (_Float16)pnx) << 16);   \
                if (!(lr & 1)) {                                                             \
                    int wo = (ROW) * 512 + (cw + NT * 16 + lr) * 2;                          \
                    *(unsigned*)(dst + SWZ(wo)) = pk;                                        \
                }                                                                            \
            }

            // ---- tile0: own rows 0..15 ----
            {
                float bl0 = (float)*(const _Float16*)(src + SWZ(16 * 512 + (cw + lr) * 2));
                float bl1 = (float)*(const _Float16*)(src + SWZ(16 * 512 + (cw + 16 + lr) * 2));
                #pragma unroll
                for (int r = 0; r < 4; ++r) {
                    const int row = q * 4 + r;
                    const int gr = 16 * h + row;
                    f32x4 gA = *(const f32x4*)(gat + row * 12);
                    f32x4 gB = *(const f32x4*)(gat + row * 12 + 4);
                    float p0 = gA[0] + gB[0] + gbi0;
                    float p1 = gA[1] + gB[1] + gbi1;
                    float p2 = gA[2] + gB[2] + gbi2;
                    if (gr < n) {
                        float mg = fmaxf(fmaxf(p0, p1), p2);
                        float ee0 = exp2f((p0 - mg) * LOG2E);
                        float ee1 = exp2f((p1 - mg) * LOG2E);
                        float ee2 = exp2f((p2 - mg) * LOG2E);
                        float inv = __builtin_amdgcn_rcpf(ee0 + ee1 + ee2);
                        float g0f = ee0 * inv, g1f = ee1 * inv, g2f = ee2 * inv;
                        EPI(a00[r], e0, wb0, bl0, s0, 0, row, true, cm0)
                        EPI(a01[r], e1, wb1, bl1, s1, 1, row, true, cm1)
                    }
                }
            }
            // ---- tile1: overlap rows 16..22-j ----
            if (t1) {
                float bl0c = (float)*(const _Float16*)(src + SWZ(32 * 512 + (cw + lr) * 2));
                float bl1c = (float)*(const _Float16*)(src + SWZ(32 * 512 + (cw + 16 + lr) * 2));
                const int wlim = 23 - j;
                #pragma unroll
                for (int r = 0; r < 4; ++r) {
                    const int row = 16 + q * 4 + r;
                    const int gr = 16 * h + row;
                    f32x4 gA = *(const f32x4*)(gat + 192 + (row - 16) * 12);
                    f32x4 gB = *(const f32x4*)(gat + 192 + (row - 16) * 12 + 4);
                    float p0 = gA[0] + gB[0] + gbi0;
                    float p1 = gA[1] + gB[1] + gbi1;
                    float p2 = gA[2] + gB[2] + gbi2;
                    if (gr < n && row < wlim) {
                        float mg = fmaxf(fmaxf(p0, p1), p2);
                        float ee0 = exp2f((p0 - mg) * LOG2E);
                        float ee1 = exp2f((p1 - mg) * LOG2E);
                        float ee2 = exp2f((p2 - mg) * LOG2E);
                        float inv = __builtin_amdgcn_rcpf(ee0 + ee1 + ee2);
                        float g0f = ee0 * inv, g1f = ee1 * inv, g2f = ee2 * inv;
                        EPI(a10[r], e0b, wb0, bl0c, s0b, 0, row, false, cm0)
                        EPI(a11[r], e1b, wb1, bl1c, s1b, 1, row, false, cm1)
                    }
                }
            }
            #undef EPI

            // col-max (own rows only) -> encoded atomic umax
            cm0 = fmaxf(cm0, __shfl_xor(cm0, 16, 64));
            cm0 = fmaxf(cm0, __shfl_xor(cm0, 32, 64));
            cm1 = fmaxf(cm1, __shfl_xor(cm1, 16, 64));
            cm1 = fmaxf(cm1, __shfl_xor(cm1, 32, 64));
            if (l < 16) {
                int bi0 = __builtin_bit_cast(int, cm0);
                int bi1 = __builtin_bit_cast(int, cm1);
                unsigned u0 = (bi0 < 0) ? ~(unsigned)bi0 : ((unsigned)bi0 | 0x80000000u);
                unsigned u1 = (bi1 < 0) ? ~(unsigned)bi1 : ((unsigned)bi1 | 0x80000000u);
                unsigned* ep = enc + ((size_t)b * L_ + (T + j + 1)) * D_ + cw;
                __hip_atomic_fetch_max(ep + l, u0, __ATOMIC_RELAXED, __HIP_MEMORY_SCOPE_AGENT);
                __hip_atomic_fetch_max(ep + 16 + l, u1, __ATOMIC_RELAXED, __HIP_MEMORY_SCOPE_AGENT);
            }
            __syncthreads();   // B2: dst complete
            { char* tmp = src; src = dst; dst = tmp; }
        }

        // ---- export rows 0..7 of level T+8 (now in src) ----
        const bool doExp = (h >= 1) && (M >= RS);
        if (doExp) {
            if (sigma >= 2 && l == 0) {
                while (__hip_atomic_load(&ackA[(b * 8 + (h - 1)) * 16],
                        __ATOMIC_RELAXED, __HIP_MEMORY_SCOPE_AGENT) < sigma - 2)
                    __builtin_amdgcn_s_sleep(1);
            }
            unsigned long long ev = *(const unsigned long long*)(src + SWZ(w * 512 + l * 8));
            __hip_atomic_store(
                brow + ((((size_t)(sigma & 1) * 32 + b) * 8 + h) * 8 + w) * 64 + l, ev,
                __ATOMIC_RELAXED, __HIP_MEMORY_SCOPE_AGENT);
            __syncthreads();   // drains vmcnt before flag
            if (tid == 0)
                __hip_atomic_store(&flagA[(b * 8 + h) * 16], sigma + 1,
                                   __ATOMIC_RELAXED, __HIP_MEMORY_SCOPE_AGENT);
        }
    }
}

extern "C" void kernel_launch(void* const* d_in, const int* in_sizes, int n_in,
                              void* d_out, int out_size, void* d_ws, size_t ws_size,
                              hipStream_t stream) {
    const float* x  = (const float*)d_in[0];
    const float* Wl = (const float*)d_in[1];
    const float* Wr = (const float*)d_in[2];
    const float* Wb = (const float*)d_in[3];
    const float* Gl = (const float*)d_in[4];
    const float* Gr = (const float*)d_in[5];
    const float* Gb = (const float*)d_in[6];
    float* out = (float*)d_out;
    char* ws = (char*)d_ws;

    _Float16* WT = (_Float16*)ws;                                    // 278,528 B
    unsigned long long* brow = (unsigned long long*)(ws + 278528);   // 2 MB
    int* flags = (int*)(ws + 278528 + 2097152);                      // 32 KB
    unsigned* enc = (unsigned*)(ws + 278528 + 2097152 + 32768);      // 4 MB

    prep_wt<<<272, 256, 0, stream>>>(Wl, Wr, Gl, Gr, WT);
    init_misc<<<B_, 256, 0, stream>>>(x, out, enc, flags);

    void* args[] = { (void*)&x, (void*)&WT, (void*)&Wb, (void*)&Gb,
                     (void*)&enc, (void*)&brow, (void*)&flags };
    hipLaunchCooperativeKernel((const void*)grcnn_main, dim3(B_ * 8), dim3(NTHR),
                               args, 0, stream);

    decode_out<<<1024, 256, 0, stream>>>(enc, out);
}

// Round 8
// 672.897 us; speedup vs baseline: 1.1938x; 1.1938x over previous
//
#include <hip/hip_runtime.h>

// GrCNN: B=32, L=128, D=256, 127 sequential levels.
// Round 8: round-6 row-slab structure (256 blocks = (b,h), 16 rows each,
// 8 waves, per-level 1-row boundary exchange) with the sync overhauled:
//  - NO per-level atomics: per-block partial col-max -> private pmax slot
//    (plain 512B store, fp16-packed); trailing decode kernel reduces over h.
//  - export row 0 directly from epilogue registers (agent-relaxed stores),
//    drained by the existing end-of-level barrier; flag = 1 store after it.
//  - ack-wait on wave 7 at top of level (parallel with wave 0 import poll).
//  - brow ring depth 4 (elasticity); waves_per_eu(2,2) frees 256 VGPRs.

#define B_ 32
#define L_ 128
#define D_ 256
#define NTHR 512
#define LOG2E 1.4426950408889634f
#define PS_SLOTS 568   // sum_{h=0}^{7} (127-16h)

typedef _Float16 half8 __attribute__((ext_vector_type(8)));
typedef float f32x4 __attribute__((ext_vector_type(4)));

#define SWZ(o)  ((o) ^ ((((o) >> 9) & 7) << 4))
#define MFMA16 __builtin_amdgcn_mfma_f32_16x16x32_f16

// ---- WT[272][512] fp16: col j -> 512 k (k<256: Wl/Gl row k, else Wr/Gr) ----
__global__ void prep_wt(const float* __restrict__ Wl, const float* __restrict__ Wr,
                        const float* __restrict__ Gl, const float* __restrict__ Gr,
                        _Float16* __restrict__ WT) {
    int j = blockIdx.x;
    for (int k = threadIdx.x; k < 512; k += 256) {
        float v = 0.f;
        if (j < 256) v = (k < 256) ? Wl[k * 256 + j] : Wr[(k - 256) * 256 + j];
        else { int jj = j - 256; if (jj < 3) v = (k < 256) ? Gl[k * 3 + jj] : Gr[(k - 256) * 3 + jj]; }
        WT[(size_t)j * 512 + k] = (_Float16)v;
    }
}

// ---- init: zero flags+acks, level-0 col max ----
__global__ void init_misc(const float* __restrict__ x, float* __restrict__ out,
                          int* __restrict__ flags) {
    int b = blockIdx.x, c = threadIdx.x;
    if (b == 0) for (int i = c; i < 2 * 256 * 16; i += 256) flags[i] = 0;
    float m = -3.4e38f;
    for (int row = 0; row < L_; ++row)
        m = fmaxf(m, x[((size_t)b * L_ + row) * D_ + c]);
    out[(size_t)b * L_ * D_ + c] = m;
}

// ---- decode: pmax (fp16-packed partials per (b,slot)) -> out levels 1..127 ----
__global__ void decode_out(const unsigned* __restrict__ pmax, float* __restrict__ out) {
    for (size_t i = (size_t)blockIdx.x * 256 + threadIdx.x; i < (size_t)32 * 127 * 256;
         i += (size_t)gridDim.x * 256) {
        int c = (int)(i & 255);
        int k = (int)((i >> 8) % 127) + 1;
        int b = (int)(i / (127 * 256));
        int hcnt = (143 - k) >> 4;              // ceil((128-k)/16)
        int dw = ((c >> 5) * 16) + (c & 15);
        int hi = (c >> 4) & 1;
        float mx = -3.4e38f;
        for (int h = 0; h < hcnt; ++h) {
            int slot = 127 * h - 8 * h * (h - 1) + (k - 1);
            unsigned u = pmax[((size_t)b * PS_SLOTS + slot) * 128 + dw];
            unsigned short us = hi ? (unsigned short)(u >> 16) : (unsigned short)(u & 0xffff);
            float v = (float)__builtin_bit_cast(_Float16, us);
            mx = fmaxf(mx, v);
        }
        out[((size_t)b * 128 + k) * 256 + c] = mx;
    }
}

__global__ __launch_bounds__(NTHR) __attribute__((amdgpu_waves_per_eu(2, 2)))
void grcnn_main(
    const float* __restrict__ x, const _Float16* __restrict__ WT,
    const float* __restrict__ Wb, const float* __restrict__ Gb,
    unsigned* __restrict__ pmax, unsigned* __restrict__ brow,
    int* __restrict__ flags)
{
    __shared__ alignas(16) char lds[2 * 8704];
    char* bufA = lds;
    char* bufB = lds + 8704;

    const int tid = threadIdx.x;
    const int b = blockIdx.x & 31, h = blockIdx.x >> 5;
    const int w = tid >> 6, l = tid & 63, lr = l & 15, q = l >> 4;
    const int cw = w * 32;

    // ---- W fragments (resident if regalloc cooperates; 2 waves/EU -> 256 cap) ----
    half8 wf0[16], wf1[16], wfg[16];
    #pragma unroll
    for (int s = 0; s < 16; ++s) {
        const _Float16* p = WT + s * 32 + q * 8;
        wf0[s] = *(const half8*)(p + (size_t)(cw + lr) * 512);
        wf1[s] = *(const half8*)(p + (size_t)(cw + 16 + lr) * 512);
        wfg[s] = *(const half8*)(p + (size_t)(256 + lr) * 512);
    }
    // one-hot extraction frags (tile NT extracts S[row][cw+NT*16+lr])
    half8 oh0 = {}, oh1 = {};
    {
        _Float16 one = (_Float16)1.0f;
        #pragma unroll
        for (int j = 0; j < 8; ++j) if (j == (lr & 7)) {
            if (q == (lr >> 3))     oh0[j] = one;
            if (q == 2 + (lr >> 3)) oh1[j] = one;
        }
    }
    const float wb0 = Wb[cw + lr], wb1 = Wb[cw + 16 + lr];
    const float gbi0 = Gb[0], gbi1 = Gb[1], gbi2 = Gb[2];

    int* flagA = flags;
    int* ackA  = flags + 256 * 16;

    // ---- stage rows 16h..16h+16 (clamped) into BOTH buffers ----
    for (int ch = tid; ch < 17 * 32; ch += NTHR) {
        int row = ch >> 5, kc = ch & 31;
        int grow = 16 * h + row; if (grow > 127) grow = 127;
        const float* xp = x + ((size_t)b * L_ + grow) * D_ + kc * 8;
        half8 v;
        #pragma unroll
        for (int j = 0; j < 8; ++j) v[j] = (_Float16)xp[j];
        int off = SWZ(row * 512 + kc * 16);
        *(half8*)(bufA + off) = v;
        *(half8*)(bufB + off) = v;
    }
    __syncthreads();

    char* src = bufA;
    char* dst = bufB;

    for (int t = 0; t < 127; ++t) {
        const int n = 127 - t;
        const int m = n - 16 * h;
        if (m <= 0) break;
        const int mm = (m > 16) ? 16 : m;
        const bool doImp = (t >= 1) && (m >= 16);
        const bool doExp = (h >= 1) && (126 - t >= 16 * h);

        // ---- wave 0: import boundary row (level-t global row 16h+16) ----
        if (w == 0 && doImp) {
            if (l == 0) {
                while (__hip_atomic_load(&flagA[(b * 8 + h + 1) * 16],
                        __ATOMIC_RELAXED, __HIP_MEMORY_SCOPE_AGENT) < t)
                    __builtin_amdgcn_s_sleep(1);
            }
            const unsigned long long* bp = (const unsigned long long*)brow
                + (((size_t)(t & 3) * 32 + b) * 8 + (h + 1)) * 64 + l;
            unsigned long long iv =
                __hip_atomic_load(bp, __ATOMIC_RELAXED, __HIP_MEMORY_SCOPE_AGENT);
            *(unsigned long long*)(src + 8192 + l * 8) = iv;   // row 16, identity swz
            if (l == 0)
                __hip_atomic_store(&ackA[(b * 8 + h) * 16], t,
                                   __ATOMIC_RELAXED, __HIP_MEMORY_SCOPE_AGENT);
        }
        // ---- wave 7: ack-gate for our ring slot (t+1)&3 (depth-4 reuse) ----
        if (w == 7 && l == 0 && doExp && t >= 4 && (t - 3) <= 127 - 16 * h) {
            while (__hip_atomic_load(&ackA[(b * 8 + (h - 1)) * 16],
                    __ATOMIC_RELAXED, __HIP_MEMORY_SCOPE_AGENT) < t - 3)
                __builtin_amdgcn_s_sleep(1);
        }

        // ---- all waves: one-hot lv extraction (rows 0..15, overlaps polls) ----
        half8 ax = *(const half8*)(src + SWZ(lr * 512 + w * 64 + q * 16));
        f32x4 z = {};
        f32x4 e0 = MFMA16(ax, oh0, z, 0, 0, 0);
        f32x4 e1 = MFMA16(ax, oh1, z, 0, 0, 0);

        __syncthreads();   // B1: boundary row visible; exports ack-cleared

        // ---- main MFMA: A spans rows lr..lr+1 (incl row 16), K=512 ----
        f32x4 a0 = {}, a1 = {}, ag = {};
        #pragma unroll
        for (int s = 0; s < 16; ++s) {
            half8 av = *(const half8*)(src + SWZ(lr * 512 + s * 64 + q * 16));
            a0 = MFMA16(av, wf0[s], a0, 0, 0, 0);
            a1 = MFMA16(av, wf1[s], a1, 0, 0, 0);
            ag = MFMA16(av, wfg[s], ag, 0, 0, 0);
        }

        // ---- epilogue ----
        int nl = (l + 16) & 63;
        float s0 = __shfl(e0[0], nl, 64);
        float s1 = __shfl(e1[0], nl, 64);
        float bl0 = (float)*(const _Float16*)(src + 8192 + (cw + lr) * 2);
        float bl1 = (float)*(const _Float16*)(src + 8192 + (cw + 16 + lr) * 2);

        float cm0 = -3.4e38f, cm1 = -3.4e38f;
        #pragma unroll
        for (int r = 0; r < 4; ++r) {
            const int row = q * 4 + r;
            float p0 = __shfl(ag[r], (l & 48) + 0, 64) + gbi0;
            float p1 = __shfl(ag[r], (l & 48) + 1, 64) + gbi1;
            float p2 = __shfl(ag[r], (l & 48) + 2, 64) + gbi2;
            if (row < mm) {
                float mg = fmaxf(fmaxf(p0, p1), p2);
                float ee0 = exp2f((p0 - mg) * LOG2E);
                float ee1 = exp2f((p1 - mg) * LOG2E);
                float ee2 = exp2f((p2 - mg) * LOG2E);
                float inv = __builtin_amdgcn_rcpf(ee0 + ee1 + ee2);
                float g0f = ee0 * inv, g1f = ee1 * inv, g2f = ee2 * inv;

                #define EPI(NT, ACC, EV, WBV, BLV, SHV, CMV) {                               \
                    float pre = ACC[r] + WBV;                                                \
                    float exx = exp2f(pre * (2.f * LOG2E));                                  \
                    float ce = 1.f - 2.f * __builtin_amdgcn_rcpf(exx + 1.f);                 \
                    float lv = EV[r];                                                        \
                    float rv = (r < 3) ? EV[(r < 3) ? r + 1 : 0] : (q < 3 ? SHV : BLV);      \
                    float nx = g0f * lv + g1f * ce + g2f * rv;                               \
                    CMV = fmaxf(CMV, nx);                                                    \
                    int pdi = __builtin_amdgcn_update_dpp(                                   \
                        0, __builtin_bit_cast(int, nx), 0xB1, 0xF, 0xF, true);               \
                    float pnx = __builtin_bit_cast(float, pdi);                              \
                    unsigned pk = (unsigned)__builtin_bit_cast(unsigned short, (_Float16)nx) \
                        | ((unsigned)__builtin_bit_cast(unsigned short, (_Float16)pnx) << 16);\
                    if (!(lr & 1)) {                                                         \
                        int wo = row * 512 + (cw + NT * 16 + lr) * 2;                        \
                        *(unsigned*)(dst + SWZ(wo)) = pk;                                    \
                        if (row == 0 && doExp) {                                             \
                            unsigned* ep = brow +                                            \
                                (((size_t)((t + 1) & 3) * 32 + b) * 8 + h) * 128             \
                                + (cw >> 1) + NT * 8 + (lr >> 1);                            \
                            __hip_atomic_store(ep, pk, __ATOMIC_RELAXED,                     \
                                               __HIP_MEMORY_SCOPE_AGENT);                    \
                        }                                                                    \
                    }                                                                        \
                }
                EPI(0, a0, e0, wb0, bl0, s0, cm0)
                EPI(1, a1, e1, wb1, bl1, s1, cm1)
                #undef EPI
            }
        }

        // col-max across q-groups -> private pmax slot (plain store, fp16 pair)
        cm0 = fmaxf(cm0, __shfl_xor(cm0, 16, 64));
        cm0 = fmaxf(cm0, __shfl_xor(cm0, 32, 64));
        cm1 = fmaxf(cm1, __shfl_xor(cm1, 16, 64));
        cm1 = fmaxf(cm1, __shfl_xor(cm1, 32, 64));
        if (l < 16) {
            unsigned ph = (unsigned)__builtin_bit_cast(unsigned short, (_Float16)cm0)
                        | ((unsigned)__builtin_bit_cast(unsigned short, (_Float16)cm1) << 16);
            int slot = 127 * h - 8 * h * (h - 1) + t;
            pmax[((size_t)b * PS_SLOTS + slot) * 128 + w * 16 + l] = ph;
        }
        __syncthreads();   // B2: dst complete, exports + pmax drained

        if (tid == 0 && doExp)
            __hip_atomic_store(&flagA[(b * 8 + h) * 16], t + 1,
                               __ATOMIC_RELAXED, __HIP_MEMORY_SCOPE_AGENT);
        { char* tmp = src; src = dst; dst = tmp; }
    }
}

extern "C" void kernel_launch(void* const* d_in, const int* in_sizes, int n_in,
                              void* d_out, int out_size, void* d_ws, size_t ws_size,
                              hipStream_t stream) {
    const float* x  = (const float*)d_in[0];
    const float* Wl = (const float*)d_in[1];
    const float* Wr = (const float*)d_in[2];
    const float* Wb = (const float*)d_in[3];
    const float* Gl = (const float*)d_in[4];
    const float* Gr = (const float*)d_in[5];
    const float* Gb = (const float*)d_in[6];
    float* out = (float*)d_out;
    char* ws = (char*)d_ws;

    _Float16* WT = (_Float16*)ws;                         // 278,528 B
    unsigned* brow = (unsigned*)(ws + 278528);            // 4*32*8*512 = 524,288 B
    int* flags = (int*)(ws + 802816);                     // 32,768 B
    unsigned* pmax = (unsigned*)(ws + 835584);            // 32*568*512 = 9,306,112 B

    prep_wt<<<272, 256, 0, stream>>>(Wl, Wr, Gl, Gr, WT);
    init_misc<<<B_, 256, 0, stream>>>(x, out, flags);

    void* args[] = { (void*)&x, (void*)&WT, (void*)&Wb, (void*)&Gb,
                     (void*)&pmax, (void*)&brow, (void*)&flags };
    hipLaunchCooperativeKernel((const void*)grcnn_main, dim3(B_ * 8), dim3(NTHR),
                               args, 0, stream);

    decode_out<<<1024, 256, 0, stream>>>(pmax, out);
}